// Round 17
// baseline (532.778 us; speedup 1.0000x reference)
//
#include <hip/hip_runtime.h>
#include <math.h>

#define NN 20000   // nodes
#define NE 320000  // edges (without self-loops)
#define TT 8       // timesteps
#define D1 256     // H*F layer-1 width
#define CD 32      // layer-2 width == LSTM hidden
#define SBLKS ((NN + 1023) / 1024)   // 20 scan blocks

// ---------------- CSR build (once per launch; edges identical across t) ----------------

__global__ __launch_bounds__(256) void k_deg(const int* __restrict__ dst, int* __restrict__ deg) {
  int e = blockIdx.x * 256 + threadIdx.x;
  if (e < NE) atomicAdd(&deg[dst[e]], 1);
}

// parallel 2-kernel scan (replaced the single-block serial scan; r12: total -20 us)
__global__ __launch_bounds__(1024) void k_scanA(const int* __restrict__ deg,
    int* __restrict__ scantmp, int* __restrict__ bsum) {
  __shared__ int sd[1024];
  int tid = threadIdx.x;
  int i = blockIdx.x * 1024 + tid;
  int v = (i < NN) ? deg[i] : 0;
  sd[tid] = v;
  __syncthreads();
  for (int off = 1; off < 1024; off <<= 1) {
    int tv = (tid >= off) ? sd[tid - off] : 0;
    __syncthreads();
    sd[tid] += tv;
    __syncthreads();
  }
  if (i < NN) scantmp[i] = sd[tid];
  if (tid == 1023) bsum[blockIdx.x] = sd[1023];
}

__global__ __launch_bounds__(1024) void k_scanB(const int* __restrict__ deg,
    const int* __restrict__ scantmp, const int* __restrict__ bsum,
    int* __restrict__ rowptr, int* __restrict__ fill) {
  int tid = threadIdx.x;
  int b = blockIdx.x;
  int pre = 0;
  for (int j = 0; j < b; ++j) pre += bsum[j];     // <= 19 iters, L2-hot
  int i = b * 1024 + tid;
  if (i < NN) {
    int incl = scantmp[i] + pre;
    rowptr[i + 1] = incl;
    fill[i] = incl - deg[i];
  }
  if (b == 0 && tid == 0) rowptr[0] = 0;
}

__global__ __launch_bounds__(256) void k_fill(const int* __restrict__ src, const int* __restrict__ dst,
                                              int* __restrict__ fill, int* __restrict__ csr) {
  int e = blockIdx.x * 256 + threadIdx.x;
  if (e < NE) {
    int pos = atomicAdd(&fill[dst[e]], 1);
    csr[pos] = src[e];
  }
}

// ---------------- one-time: folded attention vectors + weight transposes --------------------

__global__ __launch_bounds__(256) void k_prew(const float* __restrict__ W1,
    const float* __restrict__ as1, const float* __restrict__ ad1,
    const float* __restrict__ W2,
    float* __restrict__ wsrc, float* __restrict__ wdst,
    float* __restrict__ W1T, float* __restrict__ W2T) {
  int tid = threadIdx.x;
  int k = tid >> 3, h = tid & 7;
  float s = 0.f, d = 0.f;
  #pragma unroll
  for (int f = 0; f < 32; ++f) {
    float wv = W1[k * D1 + h * 32 + f];
    s = fmaf(wv, as1[h * 32 + f], s);
    d = fmaf(wv, ad1[h * 32 + f], d);
  }
  wsrc[k * 8 + h] = s;
  wdst[k * 8 + h] = d;
  for (int i = tid; i < D1 * 32; i += 256) {
    int j = i >> 5, kk = i & 31;
    W1T[i] = W1[kk * D1 + j];          // W1T[j*32+kk]
  }
  for (int i = tid; i < 32 * D1; i += 256) {
    int f = i >> 8, kk = i & 255;
    W2T[i] = W2[kk * CD + f];          // W2T[f*256+kk]
  }
}

// ---------------- logits for all t: als/ald = x @ w~ ; t = blockIdx.x & 7 -------------------

__global__ __launch_bounds__(256) void k_logits8(const float* __restrict__ x,
    const float* __restrict__ wsrc, const float* __restrict__ wdst,
    float* __restrict__ als, float* __restrict__ ald) {
  __shared__ float xs[32 * 33];
  __shared__ float wsr[256], wdr[256];
  int tid = threadIdx.x;
  int t = blockIdx.x & 7;
  int n0 = (blockIdx.x >> 3) * 32;
  const float* xt = x + (size_t)t * NN * 32;
  int nl = tid >> 3, h = tid & 7;
  for (int i = tid; i < 1024; i += 256) {
    int g = i >> 5, k = i & 31;
    xs[g * 33 + k] = xt[n0 * 32 + i];
  }
  wsr[tid] = wsrc[tid];
  wdr[tid] = wdst[tid];
  __syncthreads();
  const float* xr = xs + nl * 33;
  float as = 0.f, ad = 0.f;
  #pragma unroll
  for (int k = 0; k < 32; ++k) {
    float xv = xr[k];
    as = fmaf(xv, wsr[k * 8 + h], as);
    ad = fmaf(xv, wdr[k * 8 + h], ad);
  }
  als[(size_t)t * NN * 8 + n0 * 8 + tid] = as;
  ald[(size_t)t * NN * 8 + n0 * 8 + tid] = ad;
}

// ---------------- layer-1 gather v4: scalarized edge loop (r13: -46 us total) --------------
// readfirstlane forces n/csr[v] into SGPRs -> scalar loads + SADDR addressing; per-edge
// address math on SALU. Arithmetic bit-identical.

__global__ __launch_bounds__(256, 2) void k_gat1(const float* __restrict__ x,
    const float* __restrict__ als, const float* __restrict__ ald,
    const int* __restrict__ rowptr, const int* __restrict__ csr,
    float* __restrict__ aggx, float* __restrict__ den1) {
  int tid = threadIdx.x;
  int wv = tid >> 6, lane = tid & 63;
  int h = lane >> 3, f4 = lane & 7;
  int t = blockIdx.x & 7;
  int n = __builtin_amdgcn_readfirstlane((blockIdx.x >> 3) * 4 + wv);  // wave-uniform -> SGPR
  const float* alsb = als + (size_t)t * NN * 8;    // wave-uniform base
  const float* xb   = x   + (size_t)t * NN * 32;   // wave-uniform base
  int xo = f4 * 4;
  float adv = ald[(size_t)t * NN * 8 + n * 8 + h];
  float4 acc = make_float4(0.f, 0.f, 0.f, 0.f);
  float den = 0.f;
  int beg = rowptr[n], end = rowptr[n + 1];        // n SGPR -> s_load
  // virtual list [beg, end]: edges then self-loop at position `end`
  int v = beg;
  for (; v + 7 <= end; v += 8) {
    int s0 = __builtin_amdgcn_readfirstlane(csr[v]);      // v..v+6 < end guaranteed
    int s1 = __builtin_amdgcn_readfirstlane(csr[v + 1]);
    int s2 = __builtin_amdgcn_readfirstlane(csr[v + 2]);
    int s3 = __builtin_amdgcn_readfirstlane(csr[v + 3]);
    int s4 = __builtin_amdgcn_readfirstlane(csr[v + 4]);
    int s5 = __builtin_amdgcn_readfirstlane(csr[v + 5]);
    int s6 = __builtin_amdgcn_readfirstlane(csr[v + 6]);
    int s7 = (v + 7 < end) ? __builtin_amdgcn_readfirstlane(csr[v + 7]) : n;
    float a0 = alsb[s0 * 8 + h] + adv;
    float a1 = alsb[s1 * 8 + h] + adv;
    float a2 = alsb[s2 * 8 + h] + adv;
    float a3 = alsb[s3 * 8 + h] + adv;
    float a4 = alsb[s4 * 8 + h] + adv;
    float a5 = alsb[s5 * 8 + h] + adv;
    float a6 = alsb[s6 * 8 + h] + adv;
    float a7 = alsb[s7 * 8 + h] + adv;
    float4 x0 = *(const float4*)(xb + s0 * 32 + xo);
    float4 x1 = *(const float4*)(xb + s1 * 32 + xo);
    float4 x2 = *(const float4*)(xb + s2 * 32 + xo);
    float4 x3 = *(const float4*)(xb + s3 * 32 + xo);
    float4 x4 = *(const float4*)(xb + s4 * 32 + xo);
    float4 x5 = *(const float4*)(xb + s5 * 32 + xo);
    float4 x6 = *(const float4*)(xb + s6 * 32 + xo);
    float4 x7 = *(const float4*)(xb + s7 * 32 + xo);
    a0 = fmaxf(a0, 0.2f * a0); a1 = fmaxf(a1, 0.2f * a1);
    a2 = fmaxf(a2, 0.2f * a2); a3 = fmaxf(a3, 0.2f * a3);
    a4 = fmaxf(a4, 0.2f * a4); a5 = fmaxf(a5, 0.2f * a5);
    a6 = fmaxf(a6, 0.2f * a6); a7 = fmaxf(a7, 0.2f * a7);
    float e0 = __expf(a0), e1 = __expf(a1), e2 = __expf(a2), e3 = __expf(a3);
    float e4 = __expf(a4), e5 = __expf(a5), e6 = __expf(a6), e7 = __expf(a7);
    acc.x = fmaf(e0, x0.x, acc.x); acc.y = fmaf(e0, x0.y, acc.y);
    acc.z = fmaf(e0, x0.z, acc.z); acc.w = fmaf(e0, x0.w, acc.w);
    acc.x = fmaf(e1, x1.x, acc.x); acc.y = fmaf(e1, x1.y, acc.y);
    acc.z = fmaf(e1, x1.z, acc.z); acc.w = fmaf(e1, x1.w, acc.w);
    acc.x = fmaf(e2, x2.x, acc.x); acc.y = fmaf(e2, x2.y, acc.y);
    acc.z = fmaf(e2, x2.z, acc.z); acc.w = fmaf(e2, x2.w, acc.w);
    acc.x = fmaf(e3, x3.x, acc.x); acc.y = fmaf(e3, x3.y, acc.y);
    acc.z = fmaf(e3, x3.z, acc.z); acc.w = fmaf(e3, x3.w, acc.w);
    acc.x = fmaf(e4, x4.x, acc.x); acc.y = fmaf(e4, x4.y, acc.y);
    acc.z = fmaf(e4, x4.z, acc.z); acc.w = fmaf(e4, x4.w, acc.w);
    acc.x = fmaf(e5, x5.x, acc.x); acc.y = fmaf(e5, x5.y, acc.y);
    acc.z = fmaf(e5, x5.z, acc.z); acc.w = fmaf(e5, x5.w, acc.w);
    acc.x = fmaf(e6, x6.x, acc.x); acc.y = fmaf(e6, x6.y, acc.y);
    acc.z = fmaf(e6, x6.z, acc.z); acc.w = fmaf(e6, x6.w, acc.w);
    acc.x = fmaf(e7, x7.x, acc.x); acc.y = fmaf(e7, x7.y, acc.y);
    acc.z = fmaf(e7, x7.z, acc.z); acc.w = fmaf(e7, x7.w, acc.w);
    den += (e0 + e1 + e2 + e3) + (e4 + e5 + e6 + e7);
  }
  for (; v <= end; ++v) {                          // 0..7 leftovers (incl. self-loop)
    int s = (v < end) ? __builtin_amdgcn_readfirstlane(csr[v]) : n;
    float a = alsb[s * 8 + h] + adv;
    a = fmaxf(a, 0.2f * a);
    float e = __expf(a);
    float4 xv = *(const float4*)(xb + s * 32 + xo);
    acc.x = fmaf(e, xv.x, acc.x); acc.y = fmaf(e, xv.y, acc.y);
    acc.z = fmaf(e, xv.z, acc.z); acc.w = fmaf(e, xv.w, acc.w);
    den += e;
  }
  // aggx[t][n][h*32 + f4*4 .. +3] -- addr = base + lane*4 floats: fully coalesced
  ((float4*)(aggx + ((size_t)t * NN + n) * 256))[lane] = acc;
  if (f4 == 0) den1[((size_t)t * NN + n) * 8 + h] = den;
}

// ---------------- dense epilogue: 16-node tiles, 10 tiles/block, software-pipelined --------
// r16 ceiling arithmetic: VALU ~65 us + LDS-read ~74 us on separate pipes -> overlap floor
// ~74-80 us, measured 128. Gap = barrier-serialized staging (16KB/block global load sits
// BETWEEN barriers every tile; hbm 830 GB/s bursty). Fix: prefetch tile it+1's aggx/den1
// into registers (+17 VGPR) right after writing tile it's LDS; the loads fly under phases
// 2/3/reduce and are waited only at the next iteration's LDS write. Same barrier count,
// bit-identical arithmetic.

#define PTILES 10

__global__ __launch_bounds__(256, 1) void k_post(const float* __restrict__ aggx,
    const float* __restrict__ den1, const float* __restrict__ W1T, const float* __restrict__ b1,
    const float* __restrict__ W2T, const float* __restrict__ as2, const float* __restrict__ ad2,
    float* __restrict__ h2, float* __restrict__ al2s, float* __restrict__ al2d) {
  __shared__ float aggs[16 * 256];   // phase-2 input; aliased as part[8][16][32] in phase 3
  __shared__ float rels[16 * 256];
  __shared__ float dens[16 * 8];     // INVERSE denominators
  float* part = aggs;                // 8*16*32 == 16*256 floats exactly
  int tid = threadIdx.x;

  int u = tid & 127, grp = tid >> 7;
  int j0 = 2 * u;
  int hj = j0 >> 5;
  // one-time per block: weights + biases into registers (amortized over PTILES tiles)
  float4 w1a[8], w1b[8];
  const float4* w1p = (const float4*)(W1T + j0 * 32);
  #pragma unroll
  for (int q8 = 0; q8 < 8; ++q8) { w1a[q8] = w1p[q8]; w1b[q8] = w1p[q8 + 8]; }
  float bj0 = b1[j0], bj1 = b1[j0 + 1];
  int q = u >> 4, fp = u & 15, f0 = 2 * fp;
  float4 w2a[8], w2b[8];
  const float4* w2pa = (const float4*)(W2T + f0 * 256 + q * 32);
  const float4* w2pb = (const float4*)(W2T + (f0 + 1) * 256 + q * 32);
  #pragma unroll
  for (int q8 = 0; q8 < 8; ++q8) { w2a[q8] = w2pa[q8]; w2b[q8] = w2pb[q8]; }
  float as2f = as2[tid & 31], ad2f = ad2[tid & 31];

  // prologue: prefetch tile 0 into registers
  float4 pf[4];
  float pfd = 1.f;
  {
    int tile = blockIdx.x * PTILES;
    int t = tile & 7;
    int n0 = (tile >> 3) * 16;
    const float4* ag4 = (const float4*)(aggx + ((size_t)t * NN + n0) * 256);
    #pragma unroll
    for (int k = 0; k < 4; ++k) pf[k] = ag4[tid + k * 256];
    if (tid < 128) pfd = den1[((size_t)t * NN + n0) * 8 + tid];
  }

  for (int it = 0; it < PTILES; ++it) {
    int tile = blockIdx.x * PTILES + it;
    int t = tile & 7;
    int n0 = (tile >> 3) * 16;

    if (it > 0) __syncthreads();     // part/dens reads of prev tile done before overwrite

    // write staged registers to LDS, then issue next tile's prefetch (flies under phases)
    float4* as4 = (float4*)aggs;
    #pragma unroll
    for (int k = 0; k < 4; ++k) as4[tid + k * 256] = pf[k];
    if (tid < 128) dens[tid] = 1.f / pfd;
    if (it + 1 < PTILES) {
      int tile2 = tile + 1;
      int t2 = tile2 & 7;
      int n02 = (tile2 >> 3) * 16;
      const float4* ag4n = (const float4*)(aggx + ((size_t)t2 * NN + n02) * 256);
      #pragma unroll
      for (int k = 0; k < 4; ++k) pf[k] = ag4n[tid + k * 256];
      if (tid < 128) pfd = den1[((size_t)t2 * NN + n02) * 8 + tid];
    }
    __syncthreads();

    // phase 2: rows grp*8..+7, columns j0, j0+1 (aggs reads shared by both columns)
    #pragma unroll
    for (int g = 0; g < 8; ++g) {
      int row = grp * 8 + g;
      const float4* ar4 = (const float4*)(aggs + row * 256 + hj * 32);
      float a0 = 0.f, a1 = 0.f;
      #pragma unroll
      for (int k4 = 0; k4 < 8; ++k4) {
        float4 av = ar4[k4];
        a0 = fmaf(av.x, w1a[k4].x, fmaf(av.y, w1a[k4].y,
             fmaf(av.z, w1a[k4].z, fmaf(av.w, w1a[k4].w, a0))));
        a1 = fmaf(av.x, w1b[k4].x, fmaf(av.y, w1b[k4].y,
             fmaf(av.z, w1b[k4].z, fmaf(av.w, w1b[k4].w, a1))));
      }
      float invd = dens[row * 8 + hj];
      float2 r;
      r.x = fmaxf(fmaf(a0, invd, bj0), 0.f);
      r.y = fmaxf(fmaf(a1, invd, bj1), 0.f);
      *(float2*)(rels + row * 256 + j0) = r;
    }
    __syncthreads();   // rels ready; aggs dead -> reuse as part

    // phase 3: q-split over K (8 chunks of 32), columns f0, f0+1
    #pragma unroll
    for (int g = 0; g < 8; ++g) {
      int row = grp * 8 + g;
      const float4* r4 = (const float4*)(rels + row * 256 + q * 32);
      float a0 = 0.f, a1 = 0.f;
      #pragma unroll
      for (int jj = 0; jj < 8; ++jj) {
        float4 a4 = r4[jj];
        a0 = fmaf(a4.x, w2a[jj].x, fmaf(a4.y, w2a[jj].y,
             fmaf(a4.z, w2a[jj].z, fmaf(a4.w, w2a[jj].w, a0))));
        a1 = fmaf(a4.x, w2b[jj].x, fmaf(a4.y, w2b[jj].y,
             fmaf(a4.z, w2b[jj].z, fmaf(a4.w, w2b[jj].w, a1))));
      }
      float2 pr; pr.x = a0; pr.y = a1;
      *(float2*)(part + q * 512 + row * 32 + f0) = pr;
    }
    __syncthreads();

    // reduce over q + h2 write + layer-2 logits
    #pragma unroll
    for (int rep = 0; rep < 2; ++rep) {
      int row = (tid >> 5) + rep * 8;
      int ff = tid & 31;
      float v = 0.f;
      #pragma unroll
      for (int qq = 0; qq < 8; ++qq) v += part[qq * 512 + row * 32 + ff];
      int nn = n0 + row;
      h2[((size_t)t * NN + nn) * CD + ff] = v;
      float vs = v * as2f, vd = v * ad2f;
      #pragma unroll
      for (int m = 1; m < 32; m <<= 1) {
        vs += __shfl_xor(vs, m, 64);
        vd += __shfl_xor(vd, m, 64);
      }
      if (ff == 0) {
        al2s[(size_t)t * NN + nn] = vs;
        al2d[(size_t)t * NN + nn] = vd;
      }
    }
  }
}

// ---------------- layer-2 aggregation v2c: wave = (node, t); lane = (d, p); n scalarized ---

__global__ __launch_bounds__(256, 4) void k_agg2(const float* __restrict__ h2,
    const float* __restrict__ al2s, const float* __restrict__ al2d,
    const int* __restrict__ rowptr, const int* __restrict__ csr,
    const float* __restrict__ b2, float* __restrict__ out) {
  int tid = threadIdx.x;
  int wv = tid >> 6, lane = tid & 63;
  int d = lane >> 3, p = lane & 7;
  int t = blockIdx.x & 7;
  int n = __builtin_amdgcn_readfirstlane((blockIdx.x >> 3) * 4 + wv);
  const float* alsb = al2s + (size_t)t * NN;       // wave-uniform base
  const float* h2b  = h2 + (size_t)t * NN * 32;    // wave-uniform base
  int po = p * 4;
  float adv = al2d[(size_t)t * NN + n];
  float4 acc = make_float4(0.f, 0.f, 0.f, 0.f);
  float den = 0.f;
  int beg = rowptr[n], end = rowptr[n + 1];
  // virtual list [beg, end]: edges then self-loop at position `end`; lane d strides by 8
  for (int v = beg + d; v <= end; v += 8) {
    int s = (v < end) ? csr[v] : n;
    float a = alsb[s] + adv;
    a = fmaxf(a, 0.2f * a);
    float e = __expf(a);
    float4 u = *(const float4*)(h2b + s * 32 + po);
    acc.x = fmaf(e, u.x, acc.x);
    acc.y = fmaf(e, u.y, acc.y);
    acc.z = fmaf(e, u.z, acc.z);
    acc.w = fmaf(e, u.w, acc.w);
    den += e;
  }
  // butterfly over d (lane bits 3..5); all lanes converge to the full sums
  #pragma unroll
  for (int m = 8; m < 64; m <<= 1) {
    acc.x += __shfl_xor(acc.x, m, 64);
    acc.y += __shfl_xor(acc.y, m, 64);
    acc.z += __shfl_xor(acc.z, m, 64);
    acc.w += __shfl_xor(acc.w, m, 64);
    den   += __shfl_xor(den,   m, 64);
  }
  if (lane < 8) {
    float4 b4 = ((const float4*)b2)[p];
    float inv = 1.f / den;
    float4 o;
    o.x = fmaf(acc.x, inv, b4.x);
    o.y = fmaf(acc.y, inv, b4.y);
    o.z = fmaf(acc.z, inv, b4.z);
    o.w = fmaf(acc.w, inv, b4.w);
    ((float4*)out)[((size_t)t * NN + n) * 8 + p] = o;
  }
}

// ---------------- LSTM, all t in one kernel: weights in VGPRs, h/c in LDS ------------------
// Stores exp(hn): softmax passes need no __expf; final output bit-identical (r16).

__global__ __launch_bounds__(256) void k_lstm_all(const float* __restrict__ agg2o,
    const float* __restrict__ w_ih, const float* __restrict__ w_hh,
    const float* __restrict__ b_ih, const float* __restrict__ b_hh,
    float* __restrict__ out) {
  __shared__ float xs[16 * 32], hs[16 * 32], cs[16 * 32], pre[16 * 128];
  int tid = threadIdx.x;
  int slot = tid >> 7;
  int r = tid & 127;
  float4 wi[8], wh[8];
  const float4* wi4 = (const float4*)(w_ih + r * 32);
  const float4* wh4 = (const float4*)(w_hh + r * 32);
  #pragma unroll
  for (int q = 0; q < 8; ++q) { wi[q] = wi4[q]; wh[q] = wh4[q]; }
  float bias = b_ih[r] + b_hh[r];
  int base = blockIdx.x * 16;
  for (int i = tid; i < 512; i += 256) { hs[i] = 0.f; cs[i] = 0.f; }
  for (int t = 0; t < TT; ++t) {
    for (int i = tid; i < 512; i += 256) xs[i] = agg2o[(size_t)t * NN * 32 + base * 32 + i];
    __syncthreads();
    #pragma unroll
    for (int g = 0; g < 8; ++g) {
      int nl = slot * 8 + g;
      const float4* xv4 = (const float4*)(xs + nl * 32);
      const float4* hv4 = (const float4*)(hs + nl * 32);
      float acc = bias;
      #pragma unroll
      for (int q = 0; q < 8; ++q) {
        float4 a = xv4[q], b = hv4[q];
        acc = fmaf(a.x, wi[q].x, acc);
        acc = fmaf(a.y, wi[q].y, acc);
        acc = fmaf(a.z, wi[q].z, acc);
        acc = fmaf(a.w, wi[q].w, acc);
        acc = fmaf(b.x, wh[q].x, acc);
        acc = fmaf(b.y, wh[q].y, acc);
        acc = fmaf(b.z, wh[q].z, acc);
        acc = fmaf(b.w, wh[q].w, acc);
      }
      pre[nl * 128 + r] = acc;
    }
    __syncthreads();
    for (int i = tid; i < 512; i += 256) {
      int nl = i >> 5, k = i & 31;
      float ai = pre[nl * 128 + k];
      float af = pre[nl * 128 + 32 + k];
      float ag = pre[nl * 128 + 64 + k];
      float ao = pre[nl * 128 + 96 + k];
      float ii = 1.f / (1.f + __expf(-ai));
      float ff = 1.f / (1.f + __expf(-af));
      float gg = tanhf(ag);
      float oo = 1.f / (1.f + __expf(-ao));
      float cn = fmaf(ff, cs[i], ii * gg);
      float hn = oo * tanhf(cn);
      cs[i] = cn; hs[i] = hn;
      out[(size_t)t * NN * 32 + base * 32 + i] = __expf(hn);
    }
  }
}

// ---------------- softmax over nodes, coalesced two-pass (out holds exp(hn)) ---------------

__global__ __launch_bounds__(256) void k_sm_sum(const float* __restrict__ out, float* __restrict__ sums) {
  int t = blockIdx.y;
  const float4* b4 = (const float4*)(out + ((size_t)t * NN + blockIdx.x * 800) * CD);
  int tid = threadIdx.x;
  float4 s4 = make_float4(0.f, 0.f, 0.f, 0.f);
  for (int i = tid; i < 6400; i += 256) {
    float4 v = b4[i];
    s4.x += v.x; s4.y += v.y;
    s4.z += v.z; s4.w += v.w;
  }
  __shared__ float4 red[256];
  red[tid] = s4;
  __syncthreads();
  for (int off = 128; off >= 8; off >>= 1) {
    if (tid < off) {
      float4 o = red[tid + off];
      red[tid].x += o.x; red[tid].y += o.y; red[tid].z += o.z; red[tid].w += o.w;
    }
    __syncthreads();
  }
  if (tid < 8) {
    float4 v = red[tid];
    int c0 = tid * 4;
    atomicAdd(&sums[t * CD + c0 + 0], v.x);
    atomicAdd(&sums[t * CD + c0 + 1], v.y);
    atomicAdd(&sums[t * CD + c0 + 2], v.z);
    atomicAdd(&sums[t * CD + c0 + 3], v.w);
  }
}

__global__ __launch_bounds__(256) void k_sm_scale(float* __restrict__ out, const float* __restrict__ sums) {
  int t = blockIdx.y;
  __shared__ float inv[CD];
  int tid = threadIdx.x;
  if (tid < CD) inv[tid] = 1.f / sums[t * CD + tid];
  __syncthreads();
  float4* b4 = (float4*)(out + ((size_t)t * NN + blockIdx.x * 800) * CD);
  for (int i = tid; i < 6400; i += 256) {
    float4 v = b4[i];
    int c0 = (4 * i) & 31;
    v.x = v.x * inv[c0];
    v.y = v.y * inv[c0 + 1];
    v.z = v.z * inv[c0 + 2];
    v.w = v.w * inv[c0 + 3];
    b4[i] = v;
  }
}

// ---------------- launch ----------------

extern "C" void kernel_launch(void* const* d_in, const int* in_sizes, int n_in,
                              void* d_out, int out_size, void* d_ws, size_t ws_size,
                              hipStream_t stream) {
  const float* x   = (const float*)d_in[0];
  const float* W1  = (const float*)d_in[1];
  const float* as1 = (const float*)d_in[2];
  const float* ad1 = (const float*)d_in[3];
  const float* b1  = (const float*)d_in[4];
  const float* W2  = (const float*)d_in[5];
  const float* as2 = (const float*)d_in[6];
  const float* ad2 = (const float*)d_in[7];
  const float* b2  = (const float*)d_in[8];
  const float* wih = (const float*)d_in[9];
  const float* whh = (const float*)d_in[10];
  const float* bih = (const float*)d_in[11];
  const float* bhh = (const float*)d_in[12];
  const int*   ei  = (const int*)d_in[13];
  const int* srcp = ei;
  const int* dstp = ei + NE;
  float* out = (float*)d_out;

  float* ws = (float*)d_ws;
  float* aggx  = ws;  ws += (size_t)TT * NN * 256;   // 164 MB
  float* den1  = ws;  ws += (size_t)TT * NN * 8;
  float* al1s  = ws;  ws += (size_t)TT * NN * 8;
  float* al1d  = ws;  ws += (size_t)TT * NN * 8;
  float* h2    = ws;  ws += (size_t)TT * NN * CD;
  float* al2s  = ws;  ws += (size_t)TT * NN;
  float* al2d  = ws;  ws += (size_t)TT * NN;
  float* agg2o = ws;  ws += (size_t)TT * NN * CD;
  float* sums  = ws;  ws += TT * CD;
  float* wsrc  = ws;  ws += 256;
  float* wdst  = ws;  ws += 256;
  float* W1T   = ws;  ws += D1 * 32;
  float* W2T   = ws;  ws += 32 * D1;
  int* rowptr = (int*)ws;
  int* fill   = rowptr + NN + 1;
  int* csr    = fill + NN;
  int* deg    = csr + NE;
  int* scantmp = deg + NN;
  int* bsum    = scantmp + NN;

  hipMemsetAsync(sums, 0, TT * CD * sizeof(float), stream);
  hipMemsetAsync(deg, 0, NN * sizeof(int), stream);

  k_deg<<<(NE + 255) / 256, 256, 0, stream>>>(dstp, deg);
  k_scanA<<<SBLKS, 1024, 0, stream>>>(deg, scantmp, bsum);
  k_scanB<<<SBLKS, 1024, 0, stream>>>(deg, scantmp, bsum, rowptr, fill);
  k_fill<<<(NE + 255) / 256, 256, 0, stream>>>(srcp, dstp, fill, csr);
  k_prew<<<1, 256, 0, stream>>>(W1, as1, ad1, W2, wsrc, wdst, W1T, W2T);

  k_logits8<<<(NN / 32) * TT, 256, 0, stream>>>(x, wsrc, wdst, al1s, al1d);
  k_gat1<<<(NN / 4) * TT, 256, 0, stream>>>(x, al1s, al1d, rowptr, csr, aggx, den1);
  k_post<<<(NN / 16) * TT / PTILES, 256, 0, stream>>>(aggx, den1, W1T, b1, W2T, as2, ad2,
                                                      h2, al2s, al2d);
  k_agg2<<<(NN / 4) * TT, 256, 0, stream>>>(h2, al2s, al2d, rowptr, csr, b2, agg2o);
  k_lstm_all<<<NN / 16, 256, 0, stream>>>(agg2o, wih, whh, bih, bhh, out);

  k_sm_sum<<<dim3(25, TT), 256, 0, stream>>>(out, sums);
  k_sm_scale<<<dim3(25, TT), 256, 0, stream>>>(out, sums);
}

// Round 18
// 517.727 us; speedup vs baseline: 1.0291x; 1.0291x over previous
//
#include <hip/hip_runtime.h>
#include <math.h>

#define NN 20000   // nodes
#define NE 320000  // edges (without self-loops)
#define TT 8       // timesteps
#define D1 256     // H*F layer-1 width
#define CD 32      // layer-2 width == LSTM hidden
#define SBLKS ((NN + 1023) / 1024)   // 20 scan blocks

// ---------------- CSR build (once per launch; edges identical across t) ----------------

__global__ __launch_bounds__(256) void k_deg(const int* __restrict__ dst, int* __restrict__ deg) {
  int e = blockIdx.x * 256 + threadIdx.x;
  if (e < NE) atomicAdd(&deg[dst[e]], 1);
}

// parallel 2-kernel scan (replaced the single-block serial scan; r12: total -20 us)
__global__ __launch_bounds__(1024) void k_scanA(const int* __restrict__ deg,
    int* __restrict__ scantmp, int* __restrict__ bsum) {
  __shared__ int sd[1024];
  int tid = threadIdx.x;
  int i = blockIdx.x * 1024 + tid;
  int v = (i < NN) ? deg[i] : 0;
  sd[tid] = v;
  __syncthreads();
  for (int off = 1; off < 1024; off <<= 1) {
    int tv = (tid >= off) ? sd[tid - off] : 0;
    __syncthreads();
    sd[tid] += tv;
    __syncthreads();
  }
  if (i < NN) scantmp[i] = sd[tid];
  if (tid == 1023) bsum[blockIdx.x] = sd[1023];
}

__global__ __launch_bounds__(1024) void k_scanB(const int* __restrict__ deg,
    const int* __restrict__ scantmp, const int* __restrict__ bsum,
    int* __restrict__ rowptr, int* __restrict__ fill) {
  int tid = threadIdx.x;
  int b = blockIdx.x;
  int pre = 0;
  for (int j = 0; j < b; ++j) pre += bsum[j];     // <= 19 iters, L2-hot
  int i = b * 1024 + tid;
  if (i < NN) {
    int incl = scantmp[i] + pre;
    rowptr[i + 1] = incl;
    fill[i] = incl - deg[i];
  }
  if (b == 0 && tid == 0) rowptr[0] = 0;
}

__global__ __launch_bounds__(256) void k_fill(const int* __restrict__ src, const int* __restrict__ dst,
                                              int* __restrict__ fill, int* __restrict__ csr) {
  int e = blockIdx.x * 256 + threadIdx.x;
  if (e < NE) {
    int pos = atomicAdd(&fill[dst[e]], 1);
    csr[pos] = src[e];
  }
}

// ---------------- one-time: folded attention vectors + weight transposes --------------------

__global__ __launch_bounds__(256) void k_prew(const float* __restrict__ W1,
    const float* __restrict__ as1, const float* __restrict__ ad1,
    const float* __restrict__ W2,
    float* __restrict__ wsrc, float* __restrict__ wdst,
    float* __restrict__ W1T, float* __restrict__ W2T) {
  int tid = threadIdx.x;
  int k = tid >> 3, h = tid & 7;
  float s = 0.f, d = 0.f;
  #pragma unroll
  for (int f = 0; f < 32; ++f) {
    float wv = W1[k * D1 + h * 32 + f];
    s = fmaf(wv, as1[h * 32 + f], s);
    d = fmaf(wv, ad1[h * 32 + f], d);
  }
  wsrc[k * 8 + h] = s;
  wdst[k * 8 + h] = d;
  for (int i = tid; i < D1 * 32; i += 256) {
    int j = i >> 5, kk = i & 31;
    W1T[i] = W1[kk * D1 + j];          // W1T[j*32+kk]
  }
  for (int i = tid; i < 32 * D1; i += 256) {
    int f = i >> 8, kk = i & 255;
    W2T[i] = W2[kk * CD + f];          // W2T[f*256+kk]
  }
}

// ---------------- logits for all t: als/ald = x @ w~ ; t = blockIdx.x & 7 -------------------

__global__ __launch_bounds__(256) void k_logits8(const float* __restrict__ x,
    const float* __restrict__ wsrc, const float* __restrict__ wdst,
    float* __restrict__ als, float* __restrict__ ald) {
  __shared__ float xs[32 * 33];
  __shared__ float wsr[256], wdr[256];
  int tid = threadIdx.x;
  int t = blockIdx.x & 7;
  int n0 = (blockIdx.x >> 3) * 32;
  const float* xt = x + (size_t)t * NN * 32;
  int nl = tid >> 3, h = tid & 7;
  for (int i = tid; i < 1024; i += 256) {
    int g = i >> 5, k = i & 31;
    xs[g * 33 + k] = xt[n0 * 32 + i];
  }
  wsr[tid] = wsrc[tid];
  wdr[tid] = wdst[tid];
  __syncthreads();
  const float* xr = xs + nl * 33;
  float as = 0.f, ad = 0.f;
  #pragma unroll
  for (int k = 0; k < 32; ++k) {
    float xv = xr[k];
    as = fmaf(xv, wsr[k * 8 + h], as);
    ad = fmaf(xv, wdr[k * 8 + h], ad);
  }
  als[(size_t)t * NN * 8 + n0 * 8 + tid] = as;
  ald[(size_t)t * NN * 8 + n0 * 8 + tid] = ad;
}

// ---------------- layer-1 gather v4: scalarized edge loop (r13: -46 us total) --------------
// readfirstlane forces n/csr[v] into SGPRs -> scalar loads + SADDR addressing; per-edge
// address math on SALU. Arithmetic bit-identical.

__global__ __launch_bounds__(256, 2) void k_gat1(const float* __restrict__ x,
    const float* __restrict__ als, const float* __restrict__ ald,
    const int* __restrict__ rowptr, const int* __restrict__ csr,
    float* __restrict__ aggx, float* __restrict__ den1) {
  int tid = threadIdx.x;
  int wv = tid >> 6, lane = tid & 63;
  int h = lane >> 3, f4 = lane & 7;
  int t = blockIdx.x & 7;
  int n = __builtin_amdgcn_readfirstlane((blockIdx.x >> 3) * 4 + wv);  // wave-uniform -> SGPR
  const float* alsb = als + (size_t)t * NN * 8;    // wave-uniform base
  const float* xb   = x   + (size_t)t * NN * 32;   // wave-uniform base
  int xo = f4 * 4;
  float adv = ald[(size_t)t * NN * 8 + n * 8 + h];
  float4 acc = make_float4(0.f, 0.f, 0.f, 0.f);
  float den = 0.f;
  int beg = rowptr[n], end = rowptr[n + 1];        // n SGPR -> s_load
  // virtual list [beg, end]: edges then self-loop at position `end`
  int v = beg;
  for (; v + 7 <= end; v += 8) {
    int s0 = __builtin_amdgcn_readfirstlane(csr[v]);      // v..v+6 < end guaranteed
    int s1 = __builtin_amdgcn_readfirstlane(csr[v + 1]);
    int s2 = __builtin_amdgcn_readfirstlane(csr[v + 2]);
    int s3 = __builtin_amdgcn_readfirstlane(csr[v + 3]);
    int s4 = __builtin_amdgcn_readfirstlane(csr[v + 4]);
    int s5 = __builtin_amdgcn_readfirstlane(csr[v + 5]);
    int s6 = __builtin_amdgcn_readfirstlane(csr[v + 6]);
    int s7 = (v + 7 < end) ? __builtin_amdgcn_readfirstlane(csr[v + 7]) : n;
    float a0 = alsb[s0 * 8 + h] + adv;
    float a1 = alsb[s1 * 8 + h] + adv;
    float a2 = alsb[s2 * 8 + h] + adv;
    float a3 = alsb[s3 * 8 + h] + adv;
    float a4 = alsb[s4 * 8 + h] + adv;
    float a5 = alsb[s5 * 8 + h] + adv;
    float a6 = alsb[s6 * 8 + h] + adv;
    float a7 = alsb[s7 * 8 + h] + adv;
    float4 x0 = *(const float4*)(xb + s0 * 32 + xo);
    float4 x1 = *(const float4*)(xb + s1 * 32 + xo);
    float4 x2 = *(const float4*)(xb + s2 * 32 + xo);
    float4 x3 = *(const float4*)(xb + s3 * 32 + xo);
    float4 x4 = *(const float4*)(xb + s4 * 32 + xo);
    float4 x5 = *(const float4*)(xb + s5 * 32 + xo);
    float4 x6 = *(const float4*)(xb + s6 * 32 + xo);
    float4 x7 = *(const float4*)(xb + s7 * 32 + xo);
    a0 = fmaxf(a0, 0.2f * a0); a1 = fmaxf(a1, 0.2f * a1);
    a2 = fmaxf(a2, 0.2f * a2); a3 = fmaxf(a3, 0.2f * a3);
    a4 = fmaxf(a4, 0.2f * a4); a5 = fmaxf(a5, 0.2f * a5);
    a6 = fmaxf(a6, 0.2f * a6); a7 = fmaxf(a7, 0.2f * a7);
    float e0 = __expf(a0), e1 = __expf(a1), e2 = __expf(a2), e3 = __expf(a3);
    float e4 = __expf(a4), e5 = __expf(a5), e6 = __expf(a6), e7 = __expf(a7);
    acc.x = fmaf(e0, x0.x, acc.x); acc.y = fmaf(e0, x0.y, acc.y);
    acc.z = fmaf(e0, x0.z, acc.z); acc.w = fmaf(e0, x0.w, acc.w);
    acc.x = fmaf(e1, x1.x, acc.x); acc.y = fmaf(e1, x1.y, acc.y);
    acc.z = fmaf(e1, x1.z, acc.z); acc.w = fmaf(e1, x1.w, acc.w);
    acc.x = fmaf(e2, x2.x, acc.x); acc.y = fmaf(e2, x2.y, acc.y);
    acc.z = fmaf(e2, x2.z, acc.z); acc.w = fmaf(e2, x2.w, acc.w);
    acc.x = fmaf(e3, x3.x, acc.x); acc.y = fmaf(e3, x3.y, acc.y);
    acc.z = fmaf(e3, x3.z, acc.z); acc.w = fmaf(e3, x3.w, acc.w);
    acc.x = fmaf(e4, x4.x, acc.x); acc.y = fmaf(e4, x4.y, acc.y);
    acc.z = fmaf(e4, x4.z, acc.z); acc.w = fmaf(e4, x4.w, acc.w);
    acc.x = fmaf(e5, x5.x, acc.x); acc.y = fmaf(e5, x5.y, acc.y);
    acc.z = fmaf(e5, x5.z, acc.z); acc.w = fmaf(e5, x5.w, acc.w);
    acc.x = fmaf(e6, x6.x, acc.x); acc.y = fmaf(e6, x6.y, acc.y);
    acc.z = fmaf(e6, x6.z, acc.z); acc.w = fmaf(e6, x6.w, acc.w);
    acc.x = fmaf(e7, x7.x, acc.x); acc.y = fmaf(e7, x7.y, acc.y);
    acc.z = fmaf(e7, x7.z, acc.z); acc.w = fmaf(e7, x7.w, acc.w);
    den += (e0 + e1 + e2 + e3) + (e4 + e5 + e6 + e7);
  }
  for (; v <= end; ++v) {                          // 0..7 leftovers (incl. self-loop)
    int s = (v < end) ? __builtin_amdgcn_readfirstlane(csr[v]) : n;
    float a = alsb[s * 8 + h] + adv;
    a = fmaxf(a, 0.2f * a);
    float e = __expf(a);
    float4 xv = *(const float4*)(xb + s * 32 + xo);
    acc.x = fmaf(e, xv.x, acc.x); acc.y = fmaf(e, xv.y, acc.y);
    acc.z = fmaf(e, xv.z, acc.z); acc.w = fmaf(e, xv.w, acc.w);
    den += e;
  }
  // aggx[t][n][h*32 + f4*4 .. +3] -- addr = base + lane*4 floats: fully coalesced
  ((float4*)(aggx + ((size_t)t * NN + n) * 256))[lane] = acc;
  if (f4 == 0) den1[((size_t)t * NN + n) * 8 + h] = den;
}

// ---------------- dense epilogue: 16-node tiles, 10 tiles/block, weights resident ----------
// r14/r16: ~76% of the LDS-read floor (512 KB ds_read/tile, ~85 B/cy/CU). r17 REFUTED
// register-prefetch pipelining: the compiler's s_waitcnt vmcnt(0) before every s_barrier
// drains prefetch loads at the first barrier (no overlap possible at HIP source level),
// and holding the prefetch regs across 3 barrier phases spilled to scratch (+50 MB WRITE,
// 128 -> 146 us). This plain barrier-staged version is the verified-best structure.

#define PTILES 10

__global__ __launch_bounds__(256, 1) void k_post(const float* __restrict__ aggx,
    const float* __restrict__ den1, const float* __restrict__ W1T, const float* __restrict__ b1,
    const float* __restrict__ W2T, const float* __restrict__ as2, const float* __restrict__ ad2,
    float* __restrict__ h2, float* __restrict__ al2s, float* __restrict__ al2d) {
  __shared__ float aggs[16 * 256];   // phase-2 input; aliased as part[8][16][32] in phase 3
  __shared__ float rels[16 * 256];
  __shared__ float dens[16 * 8];     // INVERSE denominators
  float* part = aggs;                // 8*16*32 == 16*256 floats exactly
  int tid = threadIdx.x;

  int u = tid & 127, grp = tid >> 7;
  int j0 = 2 * u;
  int hj = j0 >> 5;
  // one-time per block: weights + biases into registers (amortized over PTILES tiles)
  float4 w1a[8], w1b[8];
  const float4* w1p = (const float4*)(W1T + j0 * 32);
  #pragma unroll
  for (int q8 = 0; q8 < 8; ++q8) { w1a[q8] = w1p[q8]; w1b[q8] = w1p[q8 + 8]; }
  float bj0 = b1[j0], bj1 = b1[j0 + 1];
  int q = u >> 4, fp = u & 15, f0 = 2 * fp;
  float4 w2a[8], w2b[8];
  const float4* w2pa = (const float4*)(W2T + f0 * 256 + q * 32);
  const float4* w2pb = (const float4*)(W2T + (f0 + 1) * 256 + q * 32);
  #pragma unroll
  for (int q8 = 0; q8 < 8; ++q8) { w2a[q8] = w2pa[q8]; w2b[q8] = w2pb[q8]; }
  float as2f = as2[tid & 31], ad2f = ad2[tid & 31];

  for (int it = 0; it < PTILES; ++it) {
    int tile = blockIdx.x * PTILES + it;
    int t = tile & 7;
    int n0 = (tile >> 3) * 16;

    if (it > 0) __syncthreads();     // part/dens reads of prev tile done before overwrite

    const float4* ag4 = (const float4*)(aggx + ((size_t)t * NN + n0) * 256);
    float4* as4 = (float4*)aggs;
    #pragma unroll
    for (int k = 0; k < 4; ++k) as4[tid + k * 256] = ag4[tid + k * 256];
    if (tid < 128) dens[tid] = 1.f / den1[((size_t)t * NN + n0) * 8 + tid];
    __syncthreads();

    // phase 2: rows grp*8..+7, columns j0, j0+1 (aggs reads shared by both columns)
    #pragma unroll
    for (int g = 0; g < 8; ++g) {
      int row = grp * 8 + g;
      const float4* ar4 = (const float4*)(aggs + row * 256 + hj * 32);
      float a0 = 0.f, a1 = 0.f;
      #pragma unroll
      for (int k4 = 0; k4 < 8; ++k4) {
        float4 av = ar4[k4];
        a0 = fmaf(av.x, w1a[k4].x, fmaf(av.y, w1a[k4].y,
             fmaf(av.z, w1a[k4].z, fmaf(av.w, w1a[k4].w, a0))));
        a1 = fmaf(av.x, w1b[k4].x, fmaf(av.y, w1b[k4].y,
             fmaf(av.z, w1b[k4].z, fmaf(av.w, w1b[k4].w, a1))));
      }
      float invd = dens[row * 8 + hj];
      float2 r;
      r.x = fmaxf(fmaf(a0, invd, bj0), 0.f);
      r.y = fmaxf(fmaf(a1, invd, bj1), 0.f);
      *(float2*)(rels + row * 256 + j0) = r;
    }
    __syncthreads();   // rels ready; aggs dead -> reuse as part

    // phase 3: q-split over K (8 chunks of 32), columns f0, f0+1
    #pragma unroll
    for (int g = 0; g < 8; ++g) {
      int row = grp * 8 + g;
      const float4* r4 = (const float4*)(rels + row * 256 + q * 32);
      float a0 = 0.f, a1 = 0.f;
      #pragma unroll
      for (int jj = 0; jj < 8; ++jj) {
        float4 a4 = r4[jj];
        a0 = fmaf(a4.x, w2a[jj].x, fmaf(a4.y, w2a[jj].y,
             fmaf(a4.z, w2a[jj].z, fmaf(a4.w, w2a[jj].w, a0))));
        a1 = fmaf(a4.x, w2b[jj].x, fmaf(a4.y, w2b[jj].y,
             fmaf(a4.z, w2b[jj].z, fmaf(a4.w, w2b[jj].w, a1))));
      }
      float2 pr; pr.x = a0; pr.y = a1;
      *(float2*)(part + q * 512 + row * 32 + f0) = pr;
    }
    __syncthreads();

    // reduce over q + h2 write + layer-2 logits
    #pragma unroll
    for (int rep = 0; rep < 2; ++rep) {
      int row = (tid >> 5) + rep * 8;
      int ff = tid & 31;
      float v = 0.f;
      #pragma unroll
      for (int qq = 0; qq < 8; ++qq) v += part[qq * 512 + row * 32 + ff];
      int nn = n0 + row;
      h2[((size_t)t * NN + nn) * CD + ff] = v;
      float vs = v * as2f, vd = v * ad2f;
      #pragma unroll
      for (int m = 1; m < 32; m <<= 1) {
        vs += __shfl_xor(vs, m, 64);
        vd += __shfl_xor(vd, m, 64);
      }
      if (ff == 0) {
        al2s[(size_t)t * NN + nn] = vs;
        al2d[(size_t)t * NN + nn] = vd;
      }
    }
  }
}

// ---------------- layer-2 aggregation v2c: wave = (node, t); lane = (d, p); n scalarized ---

__global__ __launch_bounds__(256, 4) void k_agg2(const float* __restrict__ h2,
    const float* __restrict__ al2s, const float* __restrict__ al2d,
    const int* __restrict__ rowptr, const int* __restrict__ csr,
    const float* __restrict__ b2, float* __restrict__ out) {
  int tid = threadIdx.x;
  int wv = tid >> 6, lane = tid & 63;
  int d = lane >> 3, p = lane & 7;
  int t = blockIdx.x & 7;
  int n = __builtin_amdgcn_readfirstlane((blockIdx.x >> 3) * 4 + wv);
  const float* alsb = al2s + (size_t)t * NN;       // wave-uniform base
  const float* h2b  = h2 + (size_t)t * NN * 32;    // wave-uniform base
  int po = p * 4;
  float adv = al2d[(size_t)t * NN + n];
  float4 acc = make_float4(0.f, 0.f, 0.f, 0.f);
  float den = 0.f;
  int beg = rowptr[n], end = rowptr[n + 1];
  // virtual list [beg, end]: edges then self-loop at position `end`; lane d strides by 8
  for (int v = beg + d; v <= end; v += 8) {
    int s = (v < end) ? csr[v] : n;
    float a = alsb[s] + adv;
    a = fmaxf(a, 0.2f * a);
    float e = __expf(a);
    float4 u = *(const float4*)(h2b + s * 32 + po);
    acc.x = fmaf(e, u.x, acc.x);
    acc.y = fmaf(e, u.y, acc.y);
    acc.z = fmaf(e, u.z, acc.z);
    acc.w = fmaf(e, u.w, acc.w);
    den += e;
  }
  // butterfly over d (lane bits 3..5); all lanes converge to the full sums
  #pragma unroll
  for (int m = 8; m < 64; m <<= 1) {
    acc.x += __shfl_xor(acc.x, m, 64);
    acc.y += __shfl_xor(acc.y, m, 64);
    acc.z += __shfl_xor(acc.z, m, 64);
    acc.w += __shfl_xor(acc.w, m, 64);
    den   += __shfl_xor(den,   m, 64);
  }
  if (lane < 8) {
    float4 b4 = ((const float4*)b2)[p];
    float inv = 1.f / den;
    float4 o;
    o.x = fmaf(acc.x, inv, b4.x);
    o.y = fmaf(acc.y, inv, b4.y);
    o.z = fmaf(acc.z, inv, b4.z);
    o.w = fmaf(acc.w, inv, b4.w);
    ((float4*)out)[((size_t)t * NN + n) * 8 + p] = o;
  }
}

// ---------------- LSTM, all t in one kernel: weights in VGPRs, h/c in LDS ------------------
// Stores exp(hn): softmax passes need no __expf; final output bit-identical (r16).

__global__ __launch_bounds__(256) void k_lstm_all(const float* __restrict__ agg2o,
    const float* __restrict__ w_ih, const float* __restrict__ w_hh,
    const float* __restrict__ b_ih, const float* __restrict__ b_hh,
    float* __restrict__ out) {
  __shared__ float xs[16 * 32], hs[16 * 32], cs[16 * 32], pre[16 * 128];
  int tid = threadIdx.x;
  int slot = tid >> 7;
  int r = tid & 127;
  float4 wi[8], wh[8];
  const float4* wi4 = (const float4*)(w_ih + r * 32);
  const float4* wh4 = (const float4*)(w_hh + r * 32);
  #pragma unroll
  for (int q = 0; q < 8; ++q) { wi[q] = wi4[q]; wh[q] = wh4[q]; }
  float bias = b_ih[r] + b_hh[r];
  int base = blockIdx.x * 16;
  for (int i = tid; i < 512; i += 256) { hs[i] = 0.f; cs[i] = 0.f; }
  for (int t = 0; t < TT; ++t) {
    for (int i = tid; i < 512; i += 256) xs[i] = agg2o[(size_t)t * NN * 32 + base * 32 + i];
    __syncthreads();
    #pragma unroll
    for (int g = 0; g < 8; ++g) {
      int nl = slot * 8 + g;
      const float4* xv4 = (const float4*)(xs + nl * 32);
      const float4* hv4 = (const float4*)(hs + nl * 32);
      float acc = bias;
      #pragma unroll
      for (int q = 0; q < 8; ++q) {
        float4 a = xv4[q], b = hv4[q];
        acc = fmaf(a.x, wi[q].x, acc);
        acc = fmaf(a.y, wi[q].y, acc);
        acc = fmaf(a.z, wi[q].z, acc);
        acc = fmaf(a.w, wi[q].w, acc);
        acc = fmaf(b.x, wh[q].x, acc);
        acc = fmaf(b.y, wh[q].y, acc);
        acc = fmaf(b.z, wh[q].z, acc);
        acc = fmaf(b.w, wh[q].w, acc);
      }
      pre[nl * 128 + r] = acc;
    }
    __syncthreads();
    for (int i = tid; i < 512; i += 256) {
      int nl = i >> 5, k = i & 31;
      float ai = pre[nl * 128 + k];
      float af = pre[nl * 128 + 32 + k];
      float ag = pre[nl * 128 + 64 + k];
      float ao = pre[nl * 128 + 96 + k];
      float ii = 1.f / (1.f + __expf(-ai));
      float ff = 1.f / (1.f + __expf(-af));
      float gg = tanhf(ag);
      float oo = 1.f / (1.f + __expf(-ao));
      float cn = fmaf(ff, cs[i], ii * gg);
      float hn = oo * tanhf(cn);
      cs[i] = cn; hs[i] = hn;
      out[(size_t)t * NN * 32 + base * 32 + i] = __expf(hn);
    }
  }
}

// ---------------- softmax over nodes, coalesced two-pass (out holds exp(hn)) ---------------

__global__ __launch_bounds__(256) void k_sm_sum(const float* __restrict__ out, float* __restrict__ sums) {
  int t = blockIdx.y;
  const float4* b4 = (const float4*)(out + ((size_t)t * NN + blockIdx.x * 800) * CD);
  int tid = threadIdx.x;
  float4 s4 = make_float4(0.f, 0.f, 0.f, 0.f);
  for (int i = tid; i < 6400; i += 256) {
    float4 v = b4[i];
    s4.x += v.x; s4.y += v.y;
    s4.z += v.z; s4.w += v.w;
  }
  __shared__ float4 red[256];
  red[tid] = s4;
  __syncthreads();
  for (int off = 128; off >= 8; off >>= 1) {
    if (tid < off) {
      float4 o = red[tid + off];
      red[tid].x += o.x; red[tid].y += o.y; red[tid].z += o.z; red[tid].w += o.w;
    }
    __syncthreads();
  }
  if (tid < 8) {
    float4 v = red[tid];
    int c0 = tid * 4;
    atomicAdd(&sums[t * CD + c0 + 0], v.x);
    atomicAdd(&sums[t * CD + c0 + 1], v.y);
    atomicAdd(&sums[t * CD + c0 + 2], v.z);
    atomicAdd(&sums[t * CD + c0 + 3], v.w);
  }
}

__global__ __launch_bounds__(256) void k_sm_scale(float* __restrict__ out, const float* __restrict__ sums) {
  int t = blockIdx.y;
  __shared__ float inv[CD];
  int tid = threadIdx.x;
  if (tid < CD) inv[tid] = 1.f / sums[t * CD + tid];
  __syncthreads();
  float4* b4 = (float4*)(out + ((size_t)t * NN + blockIdx.x * 800) * CD);
  for (int i = tid; i < 6400; i += 256) {
    float4 v = b4[i];
    int c0 = (4 * i) & 31;
    v.x = v.x * inv[c0];
    v.y = v.y * inv[c0 + 1];
    v.z = v.z * inv[c0 + 2];
    v.w = v.w * inv[c0 + 3];
    b4[i] = v;
  }
}

// ---------------- launch ----------------

extern "C" void kernel_launch(void* const* d_in, const int* in_sizes, int n_in,
                              void* d_out, int out_size, void* d_ws, size_t ws_size,
                              hipStream_t stream) {
  const float* x   = (const float*)d_in[0];
  const float* W1  = (const float*)d_in[1];
  const float* as1 = (const float*)d_in[2];
  const float* ad1 = (const float*)d_in[3];
  const float* b1  = (const float*)d_in[4];
  const float* W2  = (const float*)d_in[5];
  const float* as2 = (const float*)d_in[6];
  const float* ad2 = (const float*)d_in[7];
  const float* b2  = (const float*)d_in[8];
  const float* wih = (const float*)d_in[9];
  const float* whh = (const float*)d_in[10];
  const float* bih = (const float*)d_in[11];
  const float* bhh = (const float*)d_in[12];
  const int*   ei  = (const int*)d_in[13];
  const int* srcp = ei;
  const int* dstp = ei + NE;
  float* out = (float*)d_out;

  float* ws = (float*)d_ws;
  float* aggx  = ws;  ws += (size_t)TT * NN * 256;   // 164 MB
  float* den1  = ws;  ws += (size_t)TT * NN * 8;
  float* al1s  = ws;  ws += (size_t)TT * NN * 8;
  float* al1d  = ws;  ws += (size_t)TT * NN * 8;
  float* h2    = ws;  ws += (size_t)TT * NN * CD;
  float* al2s  = ws;  ws += (size_t)TT * NN;
  float* al2d  = ws;  ws += (size_t)TT * NN;
  float* agg2o = ws;  ws += (size_t)TT * NN * CD;
  float* sums  = ws;  ws += TT * CD;
  float* wsrc  = ws;  ws += 256;
  float* wdst  = ws;  ws += 256;
  float* W1T   = ws;  ws += D1 * 32;
  float* W2T   = ws;  ws += 32 * D1;
  int* rowptr = (int*)ws;
  int* fill   = rowptr + NN + 1;
  int* csr    = fill + NN;
  int* deg    = csr + NE;
  int* scantmp = deg + NN;
  int* bsum    = scantmp + NN;

  hipMemsetAsync(sums, 0, TT * CD * sizeof(float), stream);
  hipMemsetAsync(deg, 0, NN * sizeof(int), stream);

  k_deg<<<(NE + 255) / 256, 256, 0, stream>>>(dstp, deg);
  k_scanA<<<SBLKS, 1024, 0, stream>>>(deg, scantmp, bsum);
  k_scanB<<<SBLKS, 1024, 0, stream>>>(deg, scantmp, bsum, rowptr, fill);
  k_fill<<<(NE + 255) / 256, 256, 0, stream>>>(srcp, dstp, fill, csr);
  k_prew<<<1, 256, 0, stream>>>(W1, as1, ad1, W2, wsrc, wdst, W1T, W2T);

  k_logits8<<<(NN / 32) * TT, 256, 0, stream>>>(x, wsrc, wdst, al1s, al1d);
  k_gat1<<<(NN / 4) * TT, 256, 0, stream>>>(x, al1s, al1d, rowptr, csr, aggx, den1);
  k_post<<<(NN / 16) * TT / PTILES, 256, 0, stream>>>(aggx, den1, W1T, b1, W2T, as2, ad2,
                                                      h2, al2s, al2d);
  k_agg2<<<(NN / 4) * TT, 256, 0, stream>>>(h2, al2s, al2d, rowptr, csr, b2, agg2o);
  k_lstm_all<<<NN / 16, 256, 0, stream>>>(agg2o, wih, whh, bih, bhh, out);

  k_sm_sum<<<dim3(25, TT), 256, 0, stream>>>(out, sums);
  k_sm_scale<<<dim3(25, TT), 256, 0, stream>>>(out, sums);
}